// Round 12
// baseline (1017.876 us; speedup 1.0000x reference)
//
#include <hip/hip_runtime.h>
#include <hip/hip_bf16.h>

typedef _Float16 f16;
typedef f16   f16x8 __attribute__((ext_vector_type(8)));
typedef float f32x4 __attribute__((ext_vector_type(4)));

#define HW 36864      /* 192*192 */
#define TS 9437184    /* 256*36864 : per-plane per-batch elements */

// ---------------------------------------------------------------------------
// Pre-kernel: W (fp32 256x256) -> 3 fp16 planes: Wq, Wk, Wv
// ---------------------------------------------------------------------------
__global__ __launch_bounds__(256) void convert_w_kernel(
    const float* __restrict__ wq, const float* __restrict__ wk,
    const float* __restrict__ wv, f16* __restrict__ wp) {
  int i = blockIdx.x * 256 + threadIdx.x;  // 0 .. 65535
  wp[i]             = (f16)wq[i];
  wp[65536 + i]     = (f16)wk[i];
  wp[2 * 65536 + i] = (f16)wv[i];
}

// ---------------------------------------------------------------------------
// Stage 1: 1x1 conv GEMM  out[o,n] = sum_i W[o,i] x[i,n] + b[o]
// R11 post-mortem: per-block serial {stage->wait->compute} left HBM at 12-24%
// and the b64 transpose-writes were 8-way bank-conflicted (31.8M).
// v3: PERSISTENT blocks (12 n-tiles each, grid=(b,t)x48 strips=1152) with
// double-buffered X tile: tile i+1's 16 float4 loads issue before tile i's
// MFMA -> HBM latency hidden under compute. Staging jobs are 8 rows x 4 cols
// -> four full b128 swizzled writes per job: 8 XOR slots x 8 lanes, each slot
// fully written = conflict-free (b128 throughput floor).
// X^T swizzle: element (i,n) at byte n*512 + ((i*2) ^ ((n&7)<<4)).
// LDS 64KB, ~200 VGPR -> 2 blocks/CU (8 waves).
// ---------------------------------------------------------------------------
__global__ __launch_bounds__(256, 2) void conv1x1_kernel(
    const float* __restrict__ xq, const float* __restrict__ xk, const float* __restrict__ xv,
    const f16* __restrict__ wp,
    const float* __restrict__ bq, const float* __restrict__ bk, const float* __restrict__ bv,
    f16* __restrict__ qkv) {
  const int bid   = blockIdx.x;
  const int bt    = bid / 48;        // 0..3*NB-1
  const int strip = bid % 48;        // 0..47, 12 tiles of 64 cols each
  const int b     = bt / 3;
  const int t     = bt % 3;
  const float* __restrict__ in   = ((t == 0) ? xq : (t == 1 ? xk : xv)) + (size_t)b * TS;
  const float* __restrict__ bias = (t == 0) ? bq : (t == 1 ? bk : bv);
  const f16* __restrict__ W = wp + t * 65536;
  f16* __restrict__ outp    = qkv + (size_t)(b * 3 + t) * TS;

  const int tid = threadIdx.x;
  const int l   = tid & 63;
  const int wv  = tid >> 6;
  const int lr  = l & 15, lg = l >> 4;

  __shared__ __align__(16) char Xbuf[2][32768];

  // two staging jobs per thread: 8 channel-rows x 4 spatial-cols each
  const int iA = 8 * (tid >> 4),        cA = 4 * (tid & 15);
  const int iB = 8 * ((tid + 256) >> 4), cB = 4 * ((tid + 256) & 15);

  float4 rv[16];   // 16 float4 in flight (job A rows 0-7, job B rows 8-15)

#define ISSUE(tile) do {                                                     \
    const int n0_ = (strip * 12 + (tile)) * 64;                              \
    _Pragma("unroll") for (int j = 0; j < 8; ++j)                            \
      rv[j]     = *(const float4*)(in + (size_t)(iA + j) * HW + n0_ + cA);   \
    _Pragma("unroll") for (int j = 0; j < 8; ++j)                            \
      rv[8 + j] = *(const float4*)(in + (size_t)(iB + j) * HW + n0_ + cB);   \
  } while (0)

#define COMMIT(bufp) do {                                                    \
    char* bp_ = (bufp);                                                      \
    _Pragma("unroll") for (int d = 0; d < 4; ++d) {                          \
      union { f16 h[8]; f16x8 v8; } p;                                       \
      _Pragma("unroll") for (int j = 0; j < 8; ++j)                          \
        p.h[j] = (f16)((&rv[j].x)[d]);                                       \
      const int n = cA + d;                                                  \
      *(f16x8*)(bp_ + n * 512 + ((iA * 2) ^ ((n & 7) << 4))) = p.v8;         \
    }                                                                        \
    _Pragma("unroll") for (int d = 0; d < 4; ++d) {                          \
      union { f16 h[8]; f16x8 v8; } p;                                       \
      _Pragma("unroll") for (int j = 0; j < 8; ++j)                          \
        p.h[j] = (f16)((&rv[8 + j].x)[d]);                                   \
      const int n = cB + d;                                                  \
      *(f16x8*)(bp_ + n * 512 + ((iB * 2) ^ ((n & 7) << 4))) = p.v8;         \
    }                                                                        \
  } while (0)

  const int obase = wv * 64;
  float bz[4][4];
#pragma unroll
  for (int fo = 0; fo < 4; ++fo)
#pragma unroll
    for (int r = 0; r < 4; ++r) bz[fo][r] = bias[obase + fo * 16 + lg * 4 + r];

  char* cur = Xbuf[0];
  char* nxt = Xbuf[1];

  ISSUE(0);
  COMMIT(cur);
  __syncthreads();

  for (int it = 0; it < 12; ++it) {
    if (it < 11) ISSUE(it + 1);          // prefetch next tile (in flight over MFMA)

    const int n0 = (strip * 12 + it) * 64;
    f32x4 acc[4][4];
#pragma unroll
    for (int fo = 0; fo < 4; ++fo)
#pragma unroll
      for (int fn = 0; fn < 4; ++fn) acc[fo][fn] = (f32x4){0.f, 0.f, 0.f, 0.f};

#pragma unroll
    for (int ks = 0; ks < 8; ++ks) {
      f16x8 aw[4], bx[4];
#pragma unroll
      for (int fo = 0; fo < 4; ++fo)
        aw[fo] = *(const f16x8*)(W + (obase + fo * 16 + lr) * 256 + ks * 32 + lg * 8);
#pragma unroll
      for (int fn = 0; fn < 4; ++fn) {
        const int n = lr + 16 * fn;
        bx[fn] = *(const f16x8*)(cur + n * 512 + ((16 * (ks * 4 + lg)) ^ ((n & 7) << 4)));
      }
#pragma unroll
      for (int fo = 0; fo < 4; ++fo)
#pragma unroll
        for (int fn = 0; fn < 4; ++fn)
          acc[fo][fn] = __builtin_amdgcn_mfma_f32_16x16x32_f16(aw[fo], bx[fn], acc[fo][fn], 0, 0, 0);
    }

    // epilogue: C layout col n = lane&15, row o = 4*(lane>>4)+reg
#pragma unroll
    for (int fo = 0; fo < 4; ++fo) {
      const int orow = obase + fo * 16 + lg * 4;
#pragma unroll
      for (int fn = 0; fn < 4; ++fn)
#pragma unroll
        for (int r = 0; r < 4; ++r)
          outp[(size_t)(orow + r) * HW + n0 + 16 * fn + lr] = (f16)(acc[fo][fn][r] + bz[fo][r]);
    }

    if (it < 11) {
      COMMIT(nxt);                       // waits on prefetched rv, writes LDS
      __syncthreads();
      char* tmp = cur; cur = nxt; nxt = tmp;
    }
  }
#undef ISSUE
#undef COMMIT
}

// ---------------------------------------------------------------------------
// Stage 2: attention, 768 threads (12 waves), one block per (b,c).
// blockIdx.x = b*256 + c. [K stage + issue aq/vp] B1 [QK^T, softmax, Pf]
// B2 [Vt write] B3 [PV]. LDS 153.6 KB -> 1 block/CU. (~175us total, floor
// ~120us — minor term.)
// ---------------------------------------------------------------------------
__global__ __launch_bounds__(768) void attn_kernel(
    const f16* __restrict__ qkv, float* __restrict__ outb) {
  const int c2  = blockIdx.x;
  const int b   = c2 >> 8;
  const int c   = c2 & 255;
  const int tid = threadIdx.x;
  const int l   = tid & 63;
  const int wv  = tid >> 6;          // 0..11  == q-tile index
  const int lr  = l & 15, lg = l >> 4;

  const f16* __restrict__ qb = qkv + (size_t)(b * 3) * TS;
  const f16* __restrict__ q = qb + (size_t)c * HW;
  const f16* __restrict__ k = qb + (size_t)TS + (size_t)c * HW;
  const f16* __restrict__ v = qb + 2 * (size_t)TS + (size_t)c * HW;
  float* __restrict__ outc = outb + (size_t)b * TS + (size_t)c * HW;

  __shared__ f16 KA[192][200];   // phase1: K [g][w]   phase2: V^T [w][g]
  __shared__ f16 Pf[192][200];   // normalized P [h][g]

  const int h0 = wv * 16;

  // ---- T14 issue-early: Q fragments (consumed in QK^T)
  f16x8 aq[6];
#pragma unroll
  for (int ks = 0; ks < 6; ++ks)
    aq[ks] = *(const f16x8*)(q + (h0 + lr) * 192 + ks * 32 + lg * 8);

  // ---- T14 issue-early: scattered V-gather into regs (written to LDS later)
  const int gA = (tid % 24) * 8, wA = (tid / 24) * 4;   // job A: all threads
  const int jB = tid + 768;                              // job B: tid < 384
  const int gB = (jB % 24) * 8, wB = (jB / 24) * 4;
  uint2 vpA[8], vpB[8];
#pragma unroll
  for (int j = 0; j < 8; ++j) vpA[j] = *(const uint2*)(v + (gA + j) * 192 + wA);
  if (tid < 384) {
#pragma unroll
    for (int j = 0; j < 8; ++j) vpB[j] = *(const uint2*)(v + (gB + j) * 192 + wB);
  }

  // ---- stage K -> KA (16B chunks, coalesced; 4608 = 768*6)
#pragma unroll
  for (int jj = 0; jj < 6; ++jj) {
    int id = tid + jj * 768;
    int g = id / 24, wo = id % 24;
    *(f16x8*)&KA[g][wo * 8] = *(const f16x8*)(k + g * 192 + wo * 8);
  }
  __syncthreads();                              // B1: K visible

  {
    f32x4 S[12];
#pragma unroll
    for (int fg = 0; fg < 12; ++fg) S[fg] = (f32x4){0.f, 0.f, 0.f, 0.f};
#pragma unroll
    for (int ks = 0; ks < 6; ++ks)
#pragma unroll
      for (int fg = 0; fg < 12; ++fg) {
        f16x8 bk_ = *(const f16x8*)&KA[16 * fg + lr][ks * 32 + lg * 8];
        S[fg] = __builtin_amdgcn_mfma_f32_16x16x32_f16(aq[ks], bk_, S[fg], 0, 0, 0);
      }

    // exact softmax per row (row = 4*lg + r; 16 lanes lr hold g-chunks),
    // normalize, store to Pf in [h][g] layout (C-layout-native scatter).
#pragma unroll
    for (int r = 0; r < 4; ++r) {
      float m = S[0][r];
#pragma unroll
      for (int fg = 1; fg < 12; ++fg) m = fmaxf(m, S[fg][r]);
      m = fmaxf(m, __shfl_xor(m, 1));
      m = fmaxf(m, __shfl_xor(m, 2));
      m = fmaxf(m, __shfl_xor(m, 4));
      m = fmaxf(m, __shfl_xor(m, 8));
      float s = 0.f;
#pragma unroll
      for (int fg = 0; fg < 12; ++fg) {
        float e = __expf(S[fg][r] - m);
        S[fg][r] = e;
        s += e;
      }
      s += __shfl_xor(s, 1);
      s += __shfl_xor(s, 2);
      s += __shfl_xor(s, 4);
      s += __shfl_xor(s, 8);
      float rs = 1.f / s;
#pragma unroll
      for (int fg = 0; fg < 12; ++fg)
        Pf[h0 + lg * 4 + r][16 * fg + lr] = (f16)(S[fg][r] * rs);
    }
  }
  __syncthreads();                              // B2: all KA reads done

  // ---- write V^T into KA from the preloaded regs (conflict-free b128 rows)
  {
#pragma unroll
    for (int qd = 0; qd < 4; ++qd) {
      union { unsigned short s[8]; f16x8 vec; } u;
#pragma unroll
      for (int j = 0; j < 8; ++j) u.s[j] = ((const unsigned short*)&vpA[j])[qd];
      *(f16x8*)&KA[wA + qd][gA] = u.vec;
    }
    if (tid < 384) {
#pragma unroll
      for (int qd = 0; qd < 4; ++qd) {
        union { unsigned short s[8]; f16x8 vec; } u;
#pragma unroll
        for (int j = 0; j < 8; ++j) u.s[j] = ((const unsigned short*)&vpB[j])[qd];
        *(f16x8*)&KA[wB + qd][gB] = u.vec;
      }
    }
  }
  __syncthreads();                              // B3: V^T visible

  {
    f32x4 O[12];
#pragma unroll
    for (int fn = 0; fn < 12; ++fn) O[fn] = (f32x4){0.f, 0.f, 0.f, 0.f};

#pragma unroll
    for (int ks = 0; ks < 6; ++ks) {
      f16x8 pa = *(const f16x8*)&Pf[h0 + lr][ks * 32 + lg * 8];  // A: row h, k = g
#pragma unroll
      for (int fn = 0; fn < 12; ++fn) {
        f16x8 bv_ = *(const f16x8*)&KA[16 * fn + lr][ks * 32 + lg * 8];  // B: col w, k = g
        O[fn] = __builtin_amdgcn_mfma_f32_16x16x32_f16(pa, bv_, O[fn], 0, 0, 0);
      }
    }

#pragma unroll
    for (int fn = 0; fn < 12; ++fn)
#pragma unroll
      for (int r = 0; r < 4; ++r)
        outc[(size_t)(h0 + lg * 4 + r) * 192 + 16 * fn + lr] = O[fn][r];
  }
}

// ---------------------------------------------------------------------------
extern "C" void kernel_launch(void* const* d_in, const int* in_sizes, int n_in,
                              void* d_out, int out_size, void* d_ws, size_t ws_size,
                              hipStream_t stream) {
  const float* query = (const float*)d_in[0];
  const float* key_  = (const float*)d_in[1];
  const float* value = (const float*)d_in[2];
  const float* Wq    = (const float*)d_in[3];
  const float* bq    = (const float*)d_in[4];
  const float* Wk    = (const float*)d_in[5];
  const float* bk    = (const float*)d_in[6];
  const float* Wv    = (const float*)d_in[7];
  const float* bv    = (const float*)d_in[8];
  float* out = (float*)d_out;

  f16* wp  = (f16*)d_ws;                        // 3*65536 fp16 = 384 KB
  f16* qkv = (f16*)((char*)d_ws + 524288);

  convert_w_kernel<<<256, 256, 0, stream>>>(Wq, Wk, Wv, wp);

  const size_t need_fused = 524288 + (size_t)8 * 3 * TS * 2;  // ~453.5 MB
  if (ws_size >= need_fused) {
    // Fused: all 8 batches in one conv dispatch + one attn dispatch.
    conv1x1_kernel<<<48 * 3 * 8, 256, 0, stream>>>(
        query, key_, value, wp, bq, bk, bv, qkv);
    attn_kernel<<<2048, 768, 0, stream>>>(qkv, out);
  } else {
    // Fallback: per-batch loop (qkv holds 3 planes = 56.6 MB, reused).
    for (int b = 0; b < 8; ++b) {
      const size_t off = (size_t)b * TS;
      conv1x1_kernel<<<48 * 3, 256, 0, stream>>>(
          query + off, key_ + off, value + off, wp, bq, bk, bv, qkv);
      attn_kernel<<<256, 768, 0, stream>>>(qkv, out + off);
    }
  }
}

// Round 13
// 503.418 us; speedup vs baseline: 2.0219x; 2.0219x over previous
//
#include <hip/hip_runtime.h>
#include <hip/hip_bf16.h>

typedef _Float16 f16;
typedef f16   f16x8 __attribute__((ext_vector_type(8)));
typedef float f32x4 __attribute__((ext_vector_type(4)));

#define HW 36864      /* 192*192 */
#define TS 9437184    /* 256*36864 : per-plane per-batch elements */

// async global->LDS, 16B per lane, LDS dest = wave-uniform base + lane*16
__device__ __forceinline__ void gload16(const void* g, void* lds) {
  __builtin_amdgcn_global_load_lds(
      (const __attribute__((address_space(1))) unsigned int*)g,
      (__attribute__((address_space(3))) unsigned int*)lds, 16, 0, 0);
}

// ---------------------------------------------------------------------------
// Pre-kernel: W (fp32 256x256) -> 3 fp16 planes: Wq, Wk, Wv
// ---------------------------------------------------------------------------
__global__ __launch_bounds__(256) void convert_w_kernel(
    const float* __restrict__ wq, const float* __restrict__ wk,
    const float* __restrict__ wv, f16* __restrict__ wp) {
  int i = blockIdx.x * 256 + threadIdx.x;  // 0 .. 65535
  wp[i]             = (f16)wq[i];
  wp[65536 + i]     = (f16)wk[i];
  wp[2 * 65536 + i] = (f16)wv[i];
}

// ---------------------------------------------------------------------------
// Stage 1: 1x1 conv GEMM  out[o,n] = sum_i W[o,i] x[i,n] + b[o]
// v4 (R12 post-mortem: register-prefetch spilled at the 128-VGPR wall,
// +840MB scratch traffic; R11 was latency-starved, HBM 24%):
//  - X staged as FP32 via global_load_lds (async, zero reg footprint),
//    LDS-linear [i][64 cols]; fp32->f16 conversion at consume (same casts).
//  - 2-phase pipeline: ISSUE(t+1 -> buf^1); COMPUTE(buf); barrier; swap.
//  - Consume ds_read_b32 conflict-free via pre-swizzled global source:
//    element (i, n) stored at fp32 offset i*64 + (n ^ 8*((i>>3)&3));
//    read applies the same XOR -> 2 lanes/bank (free) both sides.
//  - 8 waves: wave w = fo-quad (w>>1) x fn-pair (w&1); acc[4][2] = 32 regs.
// 512 threads, LDS 128KB (1 blk/CU), grid 24bt x 32 strips x 18 tiles.
// ---------------------------------------------------------------------------
__global__ __launch_bounds__(512) void conv1x1_kernel(
    const float* __restrict__ xq, const float* __restrict__ xk, const float* __restrict__ xv,
    const f16* __restrict__ wp,
    const float* __restrict__ bq, const float* __restrict__ bk, const float* __restrict__ bv,
    f16* __restrict__ qkv) {
  const int bid   = blockIdx.x;
  const int bt    = bid >> 5;
  const int strip = bid & 31;        // 0..31, 18 tiles of 64 cols each
  const int b     = bt / 3;
  const int t     = bt % 3;
  const float* __restrict__ in   = ((t == 0) ? xq : (t == 1 ? xk : xv)) + (size_t)b * TS;
  const float* __restrict__ bias = (t == 0) ? bq : (t == 1 ? bk : bv);
  const f16* __restrict__ W = wp + t * 65536;
  f16* __restrict__ outp    = qkv + (size_t)(b * 3 + t) * TS;

  const int tid = threadIdx.x;
  const int l   = tid & 63;
  const int wv  = tid >> 6;          // 0..7
  const int lr  = l & 15, lg = l >> 4;

  __shared__ __align__(16) float Xbuf[2][16384];   // 2 x 64KB fp32 [i=256][n=64]

  const int fnp = wv & 1;            // fn pair: {2*fnp, 2*fnp+1}
  const int foq = wv >> 1;           // fo quad: {4*foq .. 4*foq+3}

  float bz[4][4];
#pragma unroll
  for (int ff = 0; ff < 4; ++ff)
#pragma unroll
    for (int r = 0; r < 4; ++r) bz[ff][r] = bias[(foq * 4 + ff) * 16 + lg * 4 + r];

  // stage: wave wv issues m = wv*8+jj; rows i0 = m*4 + (l>>4); 16B at
  // swizzled col 4*((l&15) ^ (((m>>1)&3)<<1)); LDS dst linear m*1024.
  auto ISSUE = [&](int tile, int bufi) {
    const int n0 = (strip * 18 + tile) * 64;
#pragma unroll
    for (int jj = 0; jj < 8; ++jj) {
      const int m   = wv * 8 + jj;
      const int i0  = m * 4 + (l >> 4);
      const int col = 4 * ((l & 15) ^ (((m >> 1) & 3) << 1));
      gload16(in + (size_t)i0 * HW + n0 + col, (char*)&Xbuf[bufi][0] + m * 1024);
    }
  };

  ISSUE(0, 0);
  __syncthreads();                   // drains vmcnt -> buf0 ready

  int cur = 0;
  for (int it = 0; it < 18; ++it) {
    if (it < 17) ISSUE(it + 1, cur ^ 1);   // async loads fly under compute

    const float* __restrict__ Xc = &Xbuf[cur][0];
    const int n0 = (strip * 18 + it) * 64;

    f32x4 acc[4][2];
#pragma unroll
    for (int ff = 0; ff < 4; ++ff)
#pragma unroll
      for (int e = 0; e < 2; ++e) acc[ff][e] = (f32x4){0.f, 0.f, 0.f, 0.f};

#pragma unroll
    for (int ks = 0; ks < 8; ++ks) {
      f16x8 bx[2];
#pragma unroll
      for (int e = 0; e < 2; ++e) {
        const int nc = lr + 16 * (fnp * 2 + e);
        union { f16 h[8]; f16x8 v; } u;
#pragma unroll
        for (int j = 0; j < 8; ++j)
          u.h[j] = (f16)Xc[(ks * 32 + lg * 8 + j) * 64 + (nc ^ (lg * 8))];
        bx[e] = u.v;
      }
      f16x8 aw[4];
#pragma unroll
      for (int ff = 0; ff < 4; ++ff)
        aw[ff] = *(const f16x8*)(W + ((foq * 4 + ff) * 16 + lr) * 256 + ks * 32 + lg * 8);
#pragma unroll
      for (int ff = 0; ff < 4; ++ff)
#pragma unroll
        for (int e = 0; e < 2; ++e)
          acc[ff][e] = __builtin_amdgcn_mfma_f32_16x16x32_f16(aw[ff], bx[e], acc[ff][e], 0, 0, 0);
    }

    // epilogue: C layout col n = lane&15, row o = 4*(lane>>4)+reg
#pragma unroll
    for (int ff = 0; ff < 4; ++ff) {
      const int orow = (foq * 4 + ff) * 16 + lg * 4;
#pragma unroll
      for (int e = 0; e < 2; ++e)
#pragma unroll
        for (int r = 0; r < 4; ++r)
          outp[(size_t)(orow + r) * HW + n0 + (fnp * 2 + e) * 16 + lr] =
              (f16)(acc[ff][e][r] + bz[ff][r]);
    }

    __syncthreads();                 // drains next-tile loads, guards buf reuse
    cur ^= 1;
  }
}

// ---------------------------------------------------------------------------
// Stage 2: attention, 768 threads (12 waves), one block per (b,c).
// blockIdx.x = b*256 + c. [K stage + issue aq/vp] B1 [QK^T, softmax, Pf]
// B2 [Vt write] B3 [PV]. LDS 153.6 KB -> 1 block/CU. (~175us total — known
// good since R11; untouched.)
// ---------------------------------------------------------------------------
__global__ __launch_bounds__(768) void attn_kernel(
    const f16* __restrict__ qkv, float* __restrict__ outb) {
  const int c2  = blockIdx.x;
  const int b   = c2 >> 8;
  const int c   = c2 & 255;
  const int tid = threadIdx.x;
  const int l   = tid & 63;
  const int wv  = tid >> 6;          // 0..11  == q-tile index
  const int lr  = l & 15, lg = l >> 4;

  const f16* __restrict__ qb = qkv + (size_t)(b * 3) * TS;
  const f16* __restrict__ q = qb + (size_t)c * HW;
  const f16* __restrict__ k = qb + (size_t)TS + (size_t)c * HW;
  const f16* __restrict__ v = qb + 2 * (size_t)TS + (size_t)c * HW;
  float* __restrict__ outc = outb + (size_t)b * TS + (size_t)c * HW;

  __shared__ f16 KA[192][200];   // phase1: K [g][w]   phase2: V^T [w][g]
  __shared__ f16 Pf[192][200];   // normalized P [h][g]

  const int h0 = wv * 16;

  // ---- T14 issue-early: Q fragments (consumed in QK^T)
  f16x8 aq[6];
#pragma unroll
  for (int ks = 0; ks < 6; ++ks)
    aq[ks] = *(const f16x8*)(q + (h0 + lr) * 192 + ks * 32 + lg * 8);

  // ---- T14 issue-early: scattered V-gather into regs (written to LDS later)
  const int gA = (tid % 24) * 8, wA = (tid / 24) * 4;   // job A: all threads
  const int jB = tid + 768;                              // job B: tid < 384
  const int gB = (jB % 24) * 8, wB = (jB / 24) * 4;
  uint2 vpA[8], vpB[8];
#pragma unroll
  for (int j = 0; j < 8; ++j) vpA[j] = *(const uint2*)(v + (gA + j) * 192 + wA);
  if (tid < 384) {
#pragma unroll
    for (int j = 0; j < 8; ++j) vpB[j] = *(const uint2*)(v + (gB + j) * 192 + wB);
  }

  // ---- stage K -> KA (16B chunks, coalesced; 4608 = 768*6)
#pragma unroll
  for (int jj = 0; jj < 6; ++jj) {
    int id = tid + jj * 768;
    int g = id / 24, wo = id % 24;
    *(f16x8*)&KA[g][wo * 8] = *(const f16x8*)(k + g * 192 + wo * 8);
  }
  __syncthreads();                              // B1: K visible

  {
    f32x4 S[12];
#pragma unroll
    for (int fg = 0; fg < 12; ++fg) S[fg] = (f32x4){0.f, 0.f, 0.f, 0.f};
#pragma unroll
    for (int ks = 0; ks < 6; ++ks)
#pragma unroll
      for (int fg = 0; fg < 12; ++fg) {
        f16x8 bk_ = *(const f16x8*)&KA[16 * fg + lr][ks * 32 + lg * 8];
        S[fg] = __builtin_amdgcn_mfma_f32_16x16x32_f16(aq[ks], bk_, S[fg], 0, 0, 0);
      }

    // exact softmax per row (row = 4*lg + r; 16 lanes lr hold g-chunks),
    // normalize, store to Pf in [h][g] layout (C-layout-native scatter).
#pragma unroll
    for (int r = 0; r < 4; ++r) {
      float m = S[0][r];
#pragma unroll
      for (int fg = 1; fg < 12; ++fg) m = fmaxf(m, S[fg][r]);
      m = fmaxf(m, __shfl_xor(m, 1));
      m = fmaxf(m, __shfl_xor(m, 2));
      m = fmaxf(m, __shfl_xor(m, 4));
      m = fmaxf(m, __shfl_xor(m, 8));
      float s = 0.f;
#pragma unroll
      for (int fg = 0; fg < 12; ++fg) {
        float e = __expf(S[fg][r] - m);
        S[fg][r] = e;
        s += e;
      }
      s += __shfl_xor(s, 1);
      s += __shfl_xor(s, 2);
      s += __shfl_xor(s, 4);
      s += __shfl_xor(s, 8);
      float rs = 1.f / s;
#pragma unroll
      for (int fg = 0; fg < 12; ++fg)
        Pf[h0 + lg * 4 + r][16 * fg + lr] = (f16)(S[fg][r] * rs);
    }
  }
  __syncthreads();                              // B2: all KA reads done

  // ---- write V^T into KA from the preloaded regs (conflict-free b128 rows)
  {
#pragma unroll
    for (int qd = 0; qd < 4; ++qd) {
      union { unsigned short s[8]; f16x8 vec; } u;
#pragma unroll
      for (int j = 0; j < 8; ++j) u.s[j] = ((const unsigned short*)&vpA[j])[qd];
      *(f16x8*)&KA[wA + qd][gA] = u.vec;
    }
    if (tid < 384) {
#pragma unroll
      for (int qd = 0; qd < 4; ++qd) {
        union { unsigned short s[8]; f16x8 vec; } u;
#pragma unroll
        for (int j = 0; j < 8; ++j) u.s[j] = ((const unsigned short*)&vpB[j])[qd];
        *(f16x8*)&KA[wB + qd][gB] = u.vec;
      }
    }
  }
  __syncthreads();                              // B3: V^T visible

  {
    f32x4 O[12];
#pragma unroll
    for (int fn = 0; fn < 12; ++fn) O[fn] = (f32x4){0.f, 0.f, 0.f, 0.f};

#pragma unroll
    for (int ks = 0; ks < 6; ++ks) {
      f16x8 pa = *(const f16x8*)&Pf[h0 + lr][ks * 32 + lg * 8];  // A: row h, k = g
#pragma unroll
      for (int fn = 0; fn < 12; ++fn) {
        f16x8 bv_ = *(const f16x8*)&KA[16 * fn + lr][ks * 32 + lg * 8];  // B: col w, k = g
        O[fn] = __builtin_amdgcn_mfma_f32_16x16x32_f16(pa, bv_, O[fn], 0, 0, 0);
      }
    }

#pragma unroll
    for (int fn = 0; fn < 12; ++fn)
#pragma unroll
      for (int r = 0; r < 4; ++r)
        outc[(size_t)(h0 + lg * 4 + r) * 192 + 16 * fn + lr] = O[fn][r];
  }
}

// ---------------------------------------------------------------------------
extern "C" void kernel_launch(void* const* d_in, const int* in_sizes, int n_in,
                              void* d_out, int out_size, void* d_ws, size_t ws_size,
                              hipStream_t stream) {
  const float* query = (const float*)d_in[0];
  const float* key_  = (const float*)d_in[1];
  const float* value = (const float*)d_in[2];
  const float* Wq    = (const float*)d_in[3];
  const float* bq    = (const float*)d_in[4];
  const float* Wk    = (const float*)d_in[5];
  const float* bk    = (const float*)d_in[6];
  const float* Wv    = (const float*)d_in[7];
  const float* bv    = (const float*)d_in[8];
  float* out = (float*)d_out;

  f16* wp  = (f16*)d_ws;                        // 3*65536 fp16 = 384 KB
  f16* qkv = (f16*)((char*)d_ws + 524288);

  convert_w_kernel<<<256, 256, 0, stream>>>(Wq, Wk, Wv, wp);

  const size_t need_fused = 524288 + (size_t)8 * 3 * TS * 2;  // ~453.5 MB
  if (ws_size >= need_fused) {
    // Fused: all 8 batches in one conv dispatch + one attn dispatch.
    conv1x1_kernel<<<32 * 3 * 8, 512, 0, stream>>>(
        query, key_, value, wp, bq, bk, bv, qkv);
    attn_kernel<<<2048, 768, 0, stream>>>(qkv, out);
  } else {
    // Fallback: per-batch loop (qkv holds 3 planes = 56.6 MB, reused).
    for (int b = 0; b < 8; ++b) {
      const size_t off = (size_t)b * TS;
      conv1x1_kernel<<<32 * 3, 512, 0, stream>>>(
          query + off, key_ + off, value + off, wp, bq, bk, bv, qkv);
      attn_kernel<<<256, 768, 0, stream>>>(qkv, out + off);
    }
  }
}